// Round 2
// baseline (950.652 us; speedup 1.0000x reference)
//
#include <hip/hip_runtime.h>
#include <cstdint>
#include <cstddef>
#include <type_traits>

// ---------------- problem constants ----------------
#define OUT_DIM    65
#define TREE_STRIDE 66
#define N_NODE     1023
#define N_INTN     511

typedef _Float16 f16;
typedef _Float16 f16x8 __attribute__((ext_vector_type(8)));
typedef _Float16 f16x4 __attribute__((ext_vector_type(4)));
typedef float    f32x4 __attribute__((ext_vector_type(4)));

template<int V> using ic = std::integral_constant<int, V>;

#define MFMA(a, b, c) __builtin_amdgcn_mfma_f32_16x16x32_f16((a), (b), (c), 0, 0, 0)

// Raw waits + barrier. BARM is an asm barrier WITH "memory" clobber so the
// compiler cannot hoist ds_read/ds_write/global_load_lds across it (the
// plain builtin s_barrier is NOT an IR memory fence).
#define WAITV4 asm volatile("s_waitcnt vmcnt(4)" ::: "memory")
#define WAITV1 asm volatile("s_waitcnt vmcnt(1)" ::: "memory")
#define WAITV0 asm volatile("s_waitcnt vmcnt(0)" ::: "memory")
#define WAITL0 asm volatile("s_waitcnt lgkmcnt(0)" ::: "memory")
#define BARM   asm volatile("s_barrier" ::: "memory")

__device__ __forceinline__ void gload_lds16(const void* g, void* l) {
  __builtin_amdgcn_global_load_lds(
      (const __attribute__((address_space(1))) void*)(uintptr_t)g,
      (__attribute__((address_space(3))) void*)(uint32_t)(uintptr_t)l, 16, 0, 0);
}

// stage one BK=32 chunk of Wt[col][K] (512 cols) into buf. seg s holds
// col=s>>2, kpart=(s^col)&3 -> 4 consecutive threads read the SAME 64-B
// global line (coalesced); frag read lands <=2-way banks (r3-verified).
__device__ __forceinline__ void stageB(const f16* __restrict__ Wt, int K, int k0,
                                       f16* __restrict__ buf, int tid) {
#pragma unroll
  for (int j = 0; j < 4; j++) {
    int s = tid + j * 512;
    int col = s >> 2;
    int kp = (s ^ col) & 3;
    gload_lds16(Wt + (long)col * K + k0 + kp * 8, buf + s * 8);
  }
}

// H swizzle: elem(row,k) at row*512 + (((k>>3) ^ (row&15))<<3) + (k&7)
template<int MT>
__device__ __forceinline__ void storeH_fn(f16* __restrict__ H, f32x4 (&acc)[MT][4],
                                          const float* __restrict__ bias,
                                          int wcb, int quad, int l16) {
#pragma unroll
  for (int mt = 0; mt < MT; mt++) {
#pragma unroll
    for (int nt = 0; nt < 4; nt++) {
      const int c0 = wcb + nt * 16 + quad * 4;
      const float4 bv = *(const float4*)(bias + c0);
      f16x4 hv;
      float v0 = acc[mt][nt][0] + bv.x; hv[0] = (f16)(v0 > 0.f ? v0 : 0.f);
      float v1 = acc[mt][nt][1] + bv.y; hv[1] = (f16)(v1 > 0.f ? v1 : 0.f);
      float v2 = acc[mt][nt][2] + bv.z; hv[2] = (f16)(v2 > 0.f ? v2 : 0.f);
      float v3 = acc[mt][nt][3] + bv.w; hv[3] = (f16)(v3 > 0.f ? v3 : 0.f);
      const int row = mt * 16 + l16;
      *(f16x4*)&H[row * 512 + (((c0 >> 3) ^ l16) << 3) + (quad & 1) * 4] = hv;
    }
  }
}

// ---------------------------------------------------------------------------
// Pipelined 512-col layer, 2 LDS buffers, register fragment double-buffer.
// Steady-state step c:
//   waitcnt vmcnt(0)  [chunk c+1 staged by THIS wave has landed]
//   s_barrier (asm, memory fence) [ALL waves' stages landed; all reads of
//                                  chunk c (done before prev lgkmcnt+this bar)
//                                  are finished -> bC reusable]
//   stage chunk c+2 into bC
//   ds_read chunk c+1 fragments from bN
//   setprio(1); 16x MFMA on chunk-c register fragments; setprio(0)
//   waitcnt lgkmcnt(0) [this wave's frag reads done before next barrier]
// One barrier per chunk (old: two). The chunk-ahead stage has a full step
// (~600 cyc ds_read+MFMA) to land -> L2 latency hidden.
// ---------------------------------------------------------------------------
template<int MT, typename GetA>
__device__ __forceinline__ void run_layer_p2(
    const f16* __restrict__ Wt, int K, const float* __restrict__ bias,
    f16* __restrict__ H, f16* __restrict__ B0, f16* __restrict__ B1,
    int tid, int wave, int quad, int l16, GetA getA)
{
  const int wcb = wave * 64;
  const f32x4 z = {0.f, 0.f, 0.f, 0.f};
  f32x4 acc[MT][4];
#pragma unroll
  for (int i = 0; i < MT; i++)
#pragma unroll
    for (int j = 0; j < 4; j++) acc[i][j] = z;

  const int nc = K >> 5;          // >= 2 always
  f16* bC = B0; f16* bN = B1;
  f16x8 afA[MT], bfA[4], afB[MT], bfB[4];

  stageB(Wt, K, 0, B0, tid);
  stageB(Wt, K, 32, B1, tid);
  WAITV4;                          // chunk 0 landed (chunk 1 still in flight)
  BARM;
#pragma unroll
  for (int nt = 0; nt < 4; nt++) {
    int col = wcb + nt * 16 + l16;
    bfA[nt] = *(const f16x8*)&bC[(col << 5) + ((quad ^ (l16 & 3)) << 3)];
  }
#pragma unroll
  for (int mt = 0; mt < MT; mt++) afA[mt] = getA(0, mt);
  WAITL0;                          // chunk-0 frag reads done before first barrier

  auto step = [&](auto PC, int c) {
    constexpr int P = decltype(PC)::value;
    f16x8 (&afC)[MT] = P ? afB : afA;
    f16x8 (&bfC)[4]  = P ? bfB : bfA;
    f16x8 (&afN)[MT] = P ? afA : afB;
    f16x8 (&bfN)[4]  = P ? bfA : bfB;
    const bool more = (c + 1 < nc);
    if (more) {
      WAITV0;                      // chunk c+1 landed (this wave's part)
      BARM;                        // everyone's part landed; bC readers done
      if (c + 2 < nc) stageB(Wt, K, (c + 2) * 32, bC, tid);
#pragma unroll
      for (int nt = 0; nt < 4; nt++) {
        int col = wcb + nt * 16 + l16;
        bfN[nt] = *(const f16x8*)&bN[(col << 5) + ((quad ^ (l16 & 3)) << 3)];
      }
#pragma unroll
      for (int mt = 0; mt < MT; mt++) afN[mt] = getA(c + 1, mt);
    }
    __builtin_amdgcn_s_setprio(1);
#pragma unroll
    for (int mt = 0; mt < MT; mt++)
#pragma unroll
      for (int nt = 0; nt < 4; nt++)
        acc[mt][nt] = MFMA(bfC[nt], afC[mt], acc[mt][nt]);  // swapped: row=l16, col=quad*4+r
    __builtin_amdgcn_s_setprio(0);
    if (more) {
      WAITL0;                      // frag reads of c+1 done before next barrier
      f16* t = bC; bC = bN; bN = t;
    }
  };

  for (int c = 0; c + 1 < nc; c += 2) {
    step(ic<0>{}, c);
    step(ic<1>{}, c + 1);
  }
  if (nc & 1) step(ic<0>{}, nc - 1);   // tail lands on even parity by construction

  __syncthreads();                 // all H/B reads of this layer done
  storeH_fn<MT>(H, acc, bias, wcb, quad, l16);
  __syncthreads();
}

// Pipelined out-layer accumulation (512 -> 65 cols, 16 chunks; waves 0..4
// stage 1 op each per chunk). Epilogue left to caller.
template<int MTO>
__device__ __forceinline__ void out_accum2(
    const f16* __restrict__ wot, const f16* __restrict__ H,
    f16* __restrict__ B0, f16* __restrict__ B1,
    int tid, int wave, int quad, int l16, f32x4 (&oacc)[5])
{
  auto stageO = [&](int c, f16* buf) {
    if (tid < 320) {
      int s = tid, col = s >> 2, kp = (s ^ col) & 3;
      gload_lds16(wot + (long)col * 512 + c * 32 + kp * 8, buf + s * 8);
    }
  };
  f16* bC = B0; f16* bN = B1;
  f16x8 oaA, oaB, obA[5], obB[5];
  const int orow = wave * 16 + l16;

  stageO(0, B0); stageO(1, B1);
  WAITV1;                          // chunk 0 landed (waves 5..7: trivially pass)
  BARM;
  if (wave < MTO) {
    oaA = *(const f16x8*)&H[orow * 512 + ((quad ^ l16) << 3)];
#pragma unroll
    for (int nt = 0; nt < 5; nt++) {
      int col = nt * 16 + l16;
      obA[nt] = *(const f16x8*)&bC[(col << 5) + ((quad ^ (l16 & 3)) << 3)];
    }
  }
  WAITL0;

  auto ostep = [&](auto PC, int c) {
    constexpr int P = decltype(PC)::value;
    f16x8 &oaC = P ? oaB : oaA;  f16x8 (&obC)[5] = P ? obB : obA;
    f16x8 &oaN = P ? oaA : oaB;  f16x8 (&obN)[5] = P ? obA : obB;
    const bool more = (c + 1 < 16);
    if (more) {
      WAITV0;
      BARM;
      if (c + 2 < 16) stageO(c + 2, bC);
      if (wave < MTO) {
        oaN = *(const f16x8*)&H[orow * 512 + ((((c + 1) * 4 + quad) ^ l16) << 3)];
#pragma unroll
        for (int nt = 0; nt < 5; nt++) {
          int col = nt * 16 + l16;
          obN[nt] = *(const f16x8*)&bN[(col << 5) + ((quad ^ (l16 & 3)) << 3)];
        }
      }
    }
    if (wave < MTO) {
      __builtin_amdgcn_s_setprio(1);
#pragma unroll
      for (int nt = 0; nt < 5; nt++)
        oacc[nt] = MFMA(oaC, obC[nt], oacc[nt]);   // normal: row=quad*4+r, col=nt*16+l16
      __builtin_amdgcn_s_setprio(0);
    }
    if (more) {
      WAITL0;
      f16* t = bC; bC = bN; bN = t;
    }
  };
  for (int c = 0; c < 16; c += 2) {
    ostep(ic<0>{}, c);
    ostep(ic<1>{}, c + 1);
  }
}

// ---------------- fused 4-layer MLP, 64 rows/block, 512 thr ----------------
// LDS: H 64KB | B0 32KB | B1 32KB = 128 KiB (proven-working size).
// Internal layer 0: X[64][232] = feats|left|right|0 ALIASED INTO H — safe
// because H is only written at storeH after the layer's final barrier, by
// which point all X reads are complete.
__global__ __launch_bounds__(512, 2) void fused_mlp(
    const float* __restrict__ feats,
    const f16* __restrict__ w0t, const float* __restrict__ b0, int Kin,
    const f16* __restrict__ w1t, const float* __restrict__ b1,
    const f16* __restrict__ w2t, const float* __restrict__ b2,
    const f16* __restrict__ wot, const float* __restrict__ bo,
    f16* __restrict__ tree, int lvl, int leaf)
{
  extern __shared__ f16 S[];
  f16* H  = S;            // 32768 f16
  f16* B0 = S + 32768;    // 16384 f16
  f16* B1 = S + 49152;    // 16384 f16
  f16* X  = H;            // [64][232] layer-0 input (internal only)

  const int tid  = threadIdx.x;
  const int wave = tid >> 6;
  const int lane = tid & 63;
  const int quad = lane >> 4;
  const int l16  = lane & 15;
  const long rowBase = (long)blockIdx.x * 64;

  long bb = 0, node0 = 0;
  if (!leaf) {
    bb = rowBase >> lvl;
    node0 = (1L << lvl) - 1 + (rowBase - (bb << lvl));
    // X rows stride 232 f16 (232%32==8 -> rows spread across banks; frag
    // reads land 2-way = free)
    const float* fsrc = feats + (bb * N_INTN + node0) * 64;
    for (int i = tid; i < 4096; i += 512) {
      int r = i >> 6, cc = i & 63;
      X[r * 232 + cc] = (f16)fsrc[i];
    }
    const f16* cs = tree + ((long)bb * N_NODE + 2 * node0 + 1) * TREE_STRIDE;
    for (int i = tid; i < 8448; i += 512) {
      int j = i / 66, col = i - j * 66;
      X[(j >> 1) * 232 + 64 + (j & 1) * 65 + col] = cs[i];
    }
    for (int i = tid; i < 2432; i += 512) {   // zero k=194..231 (avoid NaN*0)
      int r = i / 38, cc = i - r * 38;
      X[r * 232 + 194 + cc] = (f16)0.f;
    }
    __syncthreads();
  }

  // ---- layer 0 ----
  if (leaf) {
    auto getA0 = [&](int c, int mt) -> f16x8 {
      const float4* p = (const float4*)(feats + (rowBase + mt * 16 + l16) * 64 + c * 32 + quad * 8);
      float4 u0 = p[0], u1 = p[1];
      f16x8 a;
      a[0] = (f16)u0.x; a[1] = (f16)u0.y; a[2] = (f16)u0.z; a[3] = (f16)u0.w;
      a[4] = (f16)u1.x; a[5] = (f16)u1.y; a[6] = (f16)u1.z; a[7] = (f16)u1.w;
      return a;
    };
    run_layer_p2<4>(w0t, Kin, b0, H, B0, B1, tid, wave, quad, l16, getA0);
  } else {
    auto getA0 = [&](int c, int mt) -> f16x8 {
      int row = mt * 16 + l16;
      return *(const f16x8*)&X[row * 232 + c * 32 + quad * 8];  // max off 223 < 232
    };
    run_layer_p2<4>(w0t, 224, b0, H, B0, B1, tid, wave, quad, l16, getA0);
  }

  // ---- mid layers (A from H) ----
  auto getAH = [&](int c, int mt) -> f16x8 {
    int row = mt * 16 + l16;
    return *(const f16x8*)&H[row * 512 + ((((c * 4 + quad) ^ l16) << 3))];
  };
  run_layer_p2<4>(w1t, 512, b1, H, B0, B1, tid, wave, quad, l16, getAH);
  run_layer_p2<4>(w2t, 512, b2, H, B0, B1, tid, wave, quad, l16, getAH);

  // ---- out layer (512 -> 65), pipelined, waves 0..3 compute ----
  {
    const f32x4 z = {0.f, 0.f, 0.f, 0.f};
    f32x4 oacc[5];
#pragma unroll
    for (int i = 0; i < 5; i++) oacc[i] = z;
    out_accum2<4>(wot, H, B0, B1, tid, wave, quad, l16, oacc);
    if (wave < 4) {
#pragma unroll
      for (int nt = 0; nt < 5; nt++)
#pragma unroll
        for (int r = 0; r < 4; r++) {
          int col = nt * 16 + l16;
          if (col < OUT_DIM) {
            long rg = rowBase + wave * 16 + quad * 4 + r;
            float v = oacc[nt][r] + bo[col];
            long b2_ = rg >> lvl;
            long ii  = rg - (b2_ << lvl);
            long node = (1L << lvl) - 1 + ii;
            tree[(b2_ * N_NODE + node) * TREE_STRIDE + col] = (f16)v;
          }
        }
    }
  }
}

// ---------------- tail: levels 5..0, one batch element per block ----------------
__global__ __launch_bounds__(512, 2) void tail_mlp(
    const float* __restrict__ feats,
    const f16* __restrict__ w0t, const float* __restrict__ b0,
    const f16* __restrict__ w1t, const float* __restrict__ b1,
    const f16* __restrict__ w2t, const float* __restrict__ b2,
    const f16* __restrict__ wot, const float* __restrict__ bo,
    const f16* __restrict__ tree, float* __restrict__ dOut)
{
  extern __shared__ f16 S[];
  f16* H  = S;             // 16384 f16 (32 rows)
  f16* B0 = S + 16384;
  f16* B1 = S + 32768;
  f16* childA = S + 49152; // 2112 f16
  f16* childB = S + 51264; // 2112 f16  -> total 53376 f16 = 106752 B

  const int b    = blockIdx.x;
  const int tid  = threadIdx.x;
  const int wave = tid >> 6;
  const int lane = tid & 63;
  const int quad = lane >> 4;
  const int l16  = lane & 15;
  const f32x4 z = {0.f, 0.f, 0.f, 0.f};

  f16* prev = childA;
  f16* cur  = childB;

  auto getAH = [&](int c, int mt) -> f16x8 {
    int row = mt * 16 + l16;
    return *(const f16x8*)&H[row * 512 + ((((c * 4 + quad) ^ l16) << 3))];
  };

  auto level = [&](auto MTc, int l) {
    constexpr int MT = decltype(MTc)::value;
    const int M = 1 << l;
    const int nodeBase = M - 1;

    // layer 0 (K=224): A gathered from feats/tree/prev
    auto getA0 = [&](int c, int mt) -> f16x8 {
      int row = mt * 16 + l16;
      int rr = row < M ? row : (M - 1);
      int nn = nodeBase + rr;
      f16x8 a;
#pragma unroll
      for (int j = 0; j < 8; j++) {
        int k = c * 32 + quad * 8 + j;
        float v = 0.f;
        if (k < 64) {
          v = feats[((long)b * N_INTN + nn) * 64 + k];
        } else if (k < 194) {
          int cc = k - 64;
          int rgt = cc >= 65;
          int col = cc - rgt * 65;
          if (l == 5) v = (float)tree[((long)b * N_NODE + 2 * nn + 1 + rgt) * TREE_STRIDE + col];
          else        v = (float)prev[(2 * rr + rgt) * 66 + col];
        }
        a[j] = (f16)v;
      }
      return a;
    };
    run_layer_p2<MT>(w0t, 224, b0, H, B0, B1, tid, wave, quad, l16, getA0);
    run_layer_p2<MT>(w1t, 512, b1, H, B0, B1, tid, wave, quad, l16, getAH);
    run_layer_p2<MT>(w2t, 512, b2, H, B0, B1, tid, wave, quad, l16, getAH);

    // out layer
    {
      f32x4 oacc[5];
#pragma unroll
      for (int i = 0; i < 5; i++) oacc[i] = z;
      out_accum2<MT>(wot, H, B0, B1, tid, wave, quad, l16, oacc);
      if (wave < MT) {
#pragma unroll
        for (int nt = 0; nt < 5; nt++)
#pragma unroll
          for (int r = 0; r < 4; r++) {
            int col = nt * 16 + l16;
            int row = wave * 16 + quad * 4 + r;
            if (col < OUT_DIM && row < M) {
              float v = oacc[nt][r] + bo[col];
              if (l == 0) {
                if (col == 0 && row == 0) dOut[b] = v;
              } else {
                cur[row * 66 + col] = (f16)v;
              }
            }
          }
      }
      __syncthreads();   // cur visible; safe to recycle H/B next level
    }
    f16* t = prev; prev = cur; cur = t;
  };

  level(ic<2>{}, 5);
  level(ic<1>{}, 4);
  level(ic<1>{}, 3);
  level(ic<1>{}, 2);
  level(ic<1>{}, 1);
  level(ic<1>{}, 0);
}

// ---------------- merged weight transpose+cast ----------------
struct WSeg { const float* W; f16* Wt; int K, N, Kpad, start; };
struct WPack { WSeg s[8]; int total; };

__global__ void wcast_all(WPack p) {
  int idx = blockIdx.x * 256 + threadIdx.x;
  if (idx >= p.total) return;
  int si = 0;
#pragma unroll
  for (int i = 1; i < 8; i++) if (idx >= p.s[i].start) si = i;
  WSeg sg = p.s[si];
  int e = idx - sg.start;
  int n = e / sg.Kpad, k = e - n * sg.Kpad;
  float v = (n < sg.N && k < sg.K) ? sg.W[(long)k * sg.N + n] : 0.f;
  sg.Wt[e] = (f16)v;
}

// ---------------- host orchestration ----------------
extern "C" void kernel_launch(void* const* d_in, const int* in_sizes, int n_in,
                              void* d_out, int out_size, void* d_ws, size_t ws_size,
                              hipStream_t stream) {
  const float* leaf_feats     = (const float*)d_in[0];
  const float* internal_feats = (const float*)d_in[1];
  const float* lw0 = (const float*)d_in[2];
  const float* lb0 = (const float*)d_in[3];
  const float* lw1 = (const float*)d_in[4];
  const float* lb1 = (const float*)d_in[5];
  const float* lw2 = (const float*)d_in[6];
  const float* lb2 = (const float*)d_in[7];
  const float* lwo = (const float*)d_in[8];
  const float* lbo = (const float*)d_in[9];
  const float* iw0 = (const float*)d_in[10];
  const float* ib0 = (const float*)d_in[11];
  const float* iw1 = (const float*)d_in[12];
  const float* ib1 = (const float*)d_in[13];
  const float* iw2 = (const float*)d_in[14];
  const float* ib2 = (const float*)d_in[15];
  const float* iwo = (const float*)d_in[16];
  const float* ibo = (const float*)d_in[17];
  float* dOut = (float*)d_out;

  char* ws = (char*)d_ws;
  size_t off = 0;
  auto alloc = [&](size_t bytes) -> void* {
    void* p = ws + off;
    off += (bytes + 255) & ~(size_t)255;
    return p;
  };

  f16* lw0t = (f16*)alloc((size_t)512 * 64 * 2);
  f16* lw1t = (f16*)alloc((size_t)512 * 512 * 2);
  f16* lw2t = (f16*)alloc((size_t)512 * 512 * 2);
  f16* lwot = (f16*)alloc((size_t)128 * 512 * 2);
  f16* iw0t = (f16*)alloc((size_t)512 * 224 * 2);
  f16* iw1t = (f16*)alloc((size_t)512 * 512 * 2);
  f16* iw2t = (f16*)alloc((size_t)512 * 512 * 2);
  f16* iwot = (f16*)alloc((size_t)128 * 512 * 2);
  f16* tree = (f16*)alloc((size_t)256 * N_NODE * TREE_STRIDE * 2);

  WPack p;
  int cum = 0;
  auto seg = [&](int i, const float* W, f16* Wt, int K, int N, int Kpad, int Npad) {
    p.s[i] = {W, Wt, K, N, Kpad, cum};
    cum += Kpad * Npad;
  };
  seg(0, lw0, lw0t, 64, 512, 64, 512);
  seg(1, lw1, lw1t, 512, 512, 512, 512);
  seg(2, lw2, lw2t, 512, 512, 512, 512);
  seg(3, lwo, lwot, 512, 65, 512, 128);
  seg(4, iw0, iw0t, 194, 512, 224, 512);
  seg(5, iw1, iw1t, 512, 512, 512, 512);
  seg(6, iw2, iw2t, 512, 512, 512, 512);
  seg(7, iwo, iwot, 512, 65, 512, 128);
  p.total = cum;
  wcast_all<<<dim3((cum + 255) / 256), dim3(256), 0, stream>>>(p);

  static bool attrSet = false;
  if (!attrSet) {
    hipFuncSetAttribute(reinterpret_cast<const void*>(fused_mlp),
                        hipFuncAttributeMaxDynamicSharedMemorySize, 131072);
    hipFuncSetAttribute(reinterpret_cast<const void*>(tail_mlp),
                        hipFuncAttributeMaxDynamicSharedMemorySize, 106752);
    attrSet = true;
  }

  const size_t fusedShmem = 131072;   // H 64K + B0 32K + B1 32K
  const size_t tailShmem  = (size_t)(16384 + 16384 + 16384 + 2112 + 2112) * 2;

  // leaf pass: 131072 rows -> nodes 511..1022
  fused_mlp<<<dim3(2048), dim3(512), fusedShmem, stream>>>(
      leaf_feats, lw0t, lb0, 64, lw1t, lb1, lw2t, lb2, lwot, lbo, tree, 9, 1);

  // big internal levels 8..6
  for (int l = 8; l >= 6; l--) {
    long rows = 256L << l;
    fused_mlp<<<dim3((unsigned)(rows / 64)), dim3(512), fusedShmem, stream>>>(
        internal_feats, iw0t, ib0, 224, iw1t, ib1, iw2t, ib2, iwot, ibo, tree, l, 0);
  }

  // levels 5..0 in one dispatch (one block per batch element)
  tail_mlp<<<dim3(256), dim3(512), tailShmem, stream>>>(
      internal_feats, iw0t, ib0, iw1t, ib1, iw2t, ib2, iwot, ibo, tree, dOut);

  (void)in_sizes; (void)n_in; (void)out_size; (void)ws_size;
}